// Round 7
// baseline (152.514 us; speedup 1.0000x reference)
//
#include <hip/hip_runtime.h>
#include <math.h>

typedef unsigned short ushort_t;
typedef __attribute__((ext_vector_type(8))) short short8;
typedef __attribute__((ext_vector_type(4))) float f32x4;

#define B_N 4096
#define D_N 512
#define P_N 256
#define C_N 8

// workspace byte offsets
// zeroed region [0, 132352) — written only by k_cast zero-blocks, consumed by later kernels
#define TK_OFF    0                          // tk[0..7] tp tickets (uint)
#define TTK_OFF   64                         // tile tickets [32] (uint)
#define FTK_OFF   192                        // final ticket (uint)
#define P2G_OFF   256                        // p2 grouped [256] f32
#define X2_OFF    1280                       // x2 [B][C] f32 (atomic-accumulated), ends 132352
#define ZERO_BYTES 132352
// non-zeroed (overwritten before read)
#define OSSP_OFF  132352                     // omega-sumsq partials [512] f32
#define MUSUM_OFF 134400                     // per-tile sigmoid sums [32] f32
#define XB_OFF    135168                     // x bf16 [B][D]
#define OMB_OFF   (XB_OFF + B_N*D_N*2)       // omega bf16 [C][D][D]
#define TPG_OFF   (OMB_OFF + C_N*D_N*D_N*2)  // tp grouped bf16 [C][32][D]
#define UG_OFF    (TPG_OFF + P_N*D_N*2)      // u grouped bf16 [C][32][D]
#define OMBT_OFF  (UG_OFF + P_N*D_N*2)       // omega^T bf16 [C][D][D]
#define MINB_OFF  OMBT_OFF                   // minb [B][C] f32 — aliases ombT (dead after k_tpu)

#define MFMA16(a, b, c) __builtin_amdgcn_mfma_f32_16x16x32_bf16(a, b, c, 0, 0, 0)

__device__ inline ushort_t f2bf(float f) {
    union { float f; unsigned u; } v; v.f = f;
    unsigned r = v.u + 0x7FFFu + ((v.u >> 16) & 1u);
    return (ushort_t)(r >> 16);
}

// async global->LDS, 16 B per lane. LDS dst must be wave-uniform; HW writes base + lane*16.
__device__ __forceinline__ void gll16(const ushort_t* g, ushort_t* l) {
    __builtin_amdgcn_global_load_lds((const __attribute__((address_space(1))) void*)g,
                                     (__attribute__((address_space(3))) void*)l, 16, 0, 0);
}

// ---------- fused casts + workspace zeroing ----------
// blocks [0,1024): cast x; [1024,1536): cast omega (+ossp partial); [1536,1544): zero tickets/p2g/x2
__global__ void k_cast(const float* __restrict__ x, const float* __restrict__ omega,
                       ushort_t* __restrict__ xb, ushort_t* __restrict__ omb,
                       ushort_t* __restrict__ ombT, float* __restrict__ ossp,
                       char* __restrict__ zbase) {
    __shared__ ushort_t T[64][72];
    __shared__ float red[4];
    int t = threadIdx.x;
    if (blockIdx.x >= 1536) {
        int zb = blockIdx.x - 1536;
        uint4 z4 = {0, 0, 0, 0};
        for (size_t off = ((size_t)zb * 256 + t) * 16; off < (size_t)ZERO_BYTES; off += 8u * 256u * 16u)
            *(uint4*)(zbase + off) = z4;
        return;
    }
    if (blockIdx.x < 1024) {
        int idx = blockIdx.x * 256 + t;
        const float4* x4 = (const float4*)x;
        float4 a = x4[idx * 2], b = x4[idx * 2 + 1];
        union { ushort_t s[8]; uint4 v; } o;
        o.s[0] = f2bf(a.x); o.s[1] = f2bf(a.y); o.s[2] = f2bf(a.z); o.s[3] = f2bf(a.w);
        o.s[4] = f2bf(b.x); o.s[5] = f2bf(b.y); o.s[6] = f2bf(b.z); o.s[7] = f2bf(b.w);
        ((uint4*)xb)[idx] = o.v;
        return;
    }
    int bid = blockIdx.x - 1024;
    int c = bid >> 6, by = (bid >> 3) & 7, bx = bid & 7;
    int r0 = by * 64, c0 = bx * 64;
    int r = t >> 2, seg = t & 3;
    const float* src = omega + ((size_t)c * D_N + r0 + r) * D_N + c0 + seg * 16;
    float4 v0 = ((const float4*)src)[0], v1 = ((const float4*)src)[1];
    float4 v2 = ((const float4*)src)[2], v3 = ((const float4*)src)[3];
    float s = v0.x*v0.x + v0.y*v0.y + v0.z*v0.z + v0.w*v0.w
            + v1.x*v1.x + v1.y*v1.y + v1.z*v1.z + v1.w*v1.w
            + v2.x*v2.x + v2.y*v2.y + v2.z*v2.z + v2.w*v2.w
            + v3.x*v3.x + v3.y*v3.y + v3.z*v3.z + v3.w*v3.w;
    union { ushort_t s[16]; uint4 v[2]; } o;
    float vv[16] = {v0.x,v0.y,v0.z,v0.w, v1.x,v1.y,v1.z,v1.w,
                    v2.x,v2.y,v2.z,v2.w, v3.x,v3.y,v3.z,v3.w};
    #pragma unroll
    for (int j = 0; j < 16; ++j) o.s[j] = f2bf(vv[j]);
    uint4* dst = (uint4*)(omb + ((size_t)c * D_N + r0 + r) * D_N + c0 + seg * 16);
    dst[0] = o.v[0]; dst[1] = o.v[1];
    #pragma unroll
    for (int j = 0; j < 16; ++j) T[seg * 16 + j][r] = o.s[j];
    __syncthreads();
    int jr = t >> 2, sg2 = t & 3;
    uint4 w0 = *(uint4*)&T[jr][sg2 * 16];
    uint4 w1 = *(uint4*)&T[jr][sg2 * 16 + 8];
    uint4* dstT = (uint4*)(ombT + ((size_t)c * D_N + c0 + jr) * D_N + r0 + sg2 * 16);
    dstT[0] = w0; dstT[1] = w1;
    #pragma unroll
    for (int off = 32; off > 0; off >>= 1) s += __shfl_down(s, off);
    if ((t & 63) == 0) red[t >> 6] = s;
    __syncthreads();
    if (t == 0) ossp[bid] = red[0] + red[1] + red[2] + red[3];   // slot store — no atomic, no zeroing
}

// ---------- k_tpu: 128 blocks. bid<64: tp unit -> ticket; bid>=64: wait ticket, u unit ----------
// 128 blocks <= 256 CUs -> all trivially resident; ticket pattern proven (R3-R5 mega).
__global__ __launch_bounds__(256) void k_tpu(const float* __restrict__ prot,
                                             const ushort_t* __restrict__ omb,
                                             const ushort_t* __restrict__ ombT,
                                             ushort_t* __restrict__ tpg,
                                             ushort_t* __restrict__ ug,
                                             float* __restrict__ p2g,
                                             unsigned* __restrict__ tk) {
    __shared__ ushort_t As[32][72];
    __shared__ ushort_t Bs[64][72];
    int bid = blockIdx.x;
    int t = threadIdx.x, w = t >> 6, lane = t & 63;
    int g = lane >> 4, cl = lane & 15;
    f32x4 acc[2] = {{0,0,0,0},{0,0,0,0}};
    if (bid < 64) {
        int c = bid >> 3, i0 = (bid & 7) * 64;
        for (int k0 = 0; k0 < D_N; k0 += 64) {
            __syncthreads();
            {
                int m = t >> 3, seg = t & 7;
                const float* ap = prot + ((size_t)(c + 8 * m)) * D_N + k0 + seg * 8;
                float4 u0 = ((const float4*)ap)[0], u1 = ((const float4*)ap)[1];
                union { ushort_t s[8]; uint4 v; } o;
                o.s[0]=f2bf(u0.x); o.s[1]=f2bf(u0.y); o.s[2]=f2bf(u0.z); o.s[3]=f2bf(u0.w);
                o.s[4]=f2bf(u1.x); o.s[5]=f2bf(u1.y); o.s[6]=f2bf(u1.z); o.s[7]=f2bf(u1.w);
                *(uint4*)&As[m][seg * 8] = o.v;
            }
            {
                int r = t >> 2, sg = t & 3;
                const uint4* bp = (const uint4*)(omb + ((size_t)c * D_N + i0 + r) * D_N + k0 + sg * 16);
                *(uint4*)&Bs[r][sg * 16] = bp[0];
                *(uint4*)&Bs[r][sg * 16 + 8] = bp[1];
            }
            __syncthreads();
            #pragma unroll
            for (int kk = 0; kk < 2; ++kk) {
                int koff = kk * 32 + g * 8;
                short8 bfr = *(const short8*)&Bs[w * 16 + cl][koff];
                #pragma unroll
                for (int mt = 0; mt < 2; ++mt) {
                    short8 afr = *(const short8*)&As[mt * 16 + cl][koff];
                    acc[mt] = MFMA16(afr, bfr, acc[mt]);
                }
            }
        }
        #pragma unroll
        for (int mt = 0; mt < 2; ++mt)
            #pragma unroll
            for (int reg = 0; reg < 4; ++reg) {
                float v = acc[mt][reg];
                int m = mt * 16 + g * 4 + reg;
                int i = i0 + w * 16 + cl;
                tpg[((size_t)c * 32 + m) * D_N + i] = f2bf(v);
                float s = v * v;
                s += __shfl_xor(s, 1); s += __shfl_xor(s, 2);
                s += __shfl_xor(s, 4); s += __shfl_xor(s, 8);
                if (cl == 0) atomicAdd(&p2g[c * 32 + m], s);
            }
        __syncthreads();
        if (t == 0) { __threadfence(); atomicAdd(&tk[c], 1u); }
    } else {
        int u = bid - 64, c = u >> 3, j0 = (u & 7) * 64;
        if (t == 0) {
            while (atomicAdd(&tk[c], 0u) < 8u) __builtin_amdgcn_s_sleep(8);
            __threadfence();
        }
        __syncthreads();
        for (int k0 = 0; k0 < D_N; k0 += 64) {
            __syncthreads();
            {
                int m = t >> 3, seg = t & 7;
                *(uint4*)&As[m][seg * 8] =
                    *(const uint4*)(tpg + ((size_t)c * 32 + m) * D_N + k0 + seg * 8);
            }
            {
                int r = t >> 2, sg = t & 3;
                const uint4* bp = (const uint4*)(ombT + ((size_t)c * D_N + j0 + r) * D_N + k0 + sg * 16);
                *(uint4*)&Bs[r][sg * 16] = bp[0];
                *(uint4*)&Bs[r][sg * 16 + 8] = bp[1];
            }
            __syncthreads();
            #pragma unroll
            for (int kk = 0; kk < 2; ++kk) {
                int koff = kk * 32 + g * 8;
                short8 bfr = *(const short8*)&Bs[w * 16 + cl][koff];
                #pragma unroll
                for (int mt = 0; mt < 2; ++mt) {
                    short8 afr = *(const short8*)&As[mt * 16 + cl][koff];
                    acc[mt] = MFMA16(afr, bfr, acc[mt]);
                }
            }
        }
        #pragma unroll
        for (int mt = 0; mt < 2; ++mt)
            #pragma unroll
            for (int reg = 0; reg < 4; ++reg) {
                int m = mt * 16 + g * 4 + reg;
                int j = j0 + w * 16 + cl;
                ug[((size_t)c * 32 + m) * D_N + j] = f2bf(acc[mt][reg]);
            }
    }
}

// ---------- k_x2dm: fused x2 + dots-min + per-tile mu + final. grid (5, 8, 32) ----------
// bx 0..3: x2 tile (128b x 128i), counted-vmcnt pipeline (R6-proven).
// bx == 4: dots slice (R0-proven).
// Tail: per-tile ticket (40 contributors) -> 40th block computes mu for the 128 rows;
// final ticket (32 tiles) -> last block reduces musum[32] + ossp[512] -> out[0].
__global__ __attribute__((amdgpu_flat_work_group_size(256, 256), amdgpu_waves_per_eu(3, 3)))
void k_x2dm(const ushort_t* __restrict__ xb,
            const ushort_t* __restrict__ omb,
            const ushort_t* __restrict__ ug,
            const float* __restrict__ p2g,
            float* __restrict__ x2,
            float* __restrict__ minb,
            const int* __restrict__ y,
            const float* __restrict__ ossp,
            float* __restrict__ musum,
            unsigned* __restrict__ ttk,
            unsigned* __restrict__ ftk,
            float* __restrict__ out) {
    int c  = blockIdx.y;
    int z  = blockIdx.z;
    int b0 = z * 128;
    int t = threadIdx.x, w = t >> 6, lane = t & 63;
    int g = lane >> 4, cl = lane & 15;
    int srow = lane >> 2, spos = lane & 3;

    __shared__ ushort_t Xs[2][128][32];
    __shared__ ushort_t Os[2][128][32];      // dots path uses rows 0..31 as Us
    __shared__ float red[128][2];
    __shared__ float rr[4], rr2[4];
    __shared__ bool flg1, flg2;

    if (blockIdx.x < 4) {
        int i0 = blockIdx.x * 128;
        int qr = w >> 1, qc = w & 1;
        f32x4 acc[4][4];
        #pragma unroll
        for (int mt = 0; mt < 4; ++mt)
            #pragma unroll
            for (int nt = 0; nt < 4; ++nt) acc[mt][nt] = (f32x4){0,0,0,0};

        #define STG(bf, k1) do {                                                        \
            _Pragma("unroll")                                                           \
            for (int i = 0; i < 2; ++i) {                                               \
                int rb = w * 32 + i * 16;                                               \
                int r  = rb + srow;                                                     \
                int cg = (spos + r) & 3;                                                \
                gll16(xb + (size_t)(b0 + r) * D_N + (k1) + cg * 8, &Xs[bf][rb][0]);     \
                gll16(omb + ((size_t)c * D_N + i0 + r) * D_N + (k1) + cg * 8,           \
                      &Os[bf][rb][0]);                                                  \
            } } while (0)

        #define CMP(cb) do {                                                            \
            short8 a_[4], b_[4];                                                        \
            _Pragma("unroll")                                                           \
            for (int mt = 0; mt < 4; ++mt) {                                            \
                int r = qr * 64 + mt * 16 + cl;                                         \
                a_[mt] = *(const short8*)&Xs[cb][r][((g - r) & 3) * 8];                 \
            }                                                                           \
            _Pragma("unroll")                                                           \
            for (int nt = 0; nt < 4; ++nt) {                                            \
                int r = qc * 64 + nt * 16 + cl;                                         \
                b_[nt] = *(const short8*)&Os[cb][r][((g - r) & 3) * 8];                 \
            }                                                                           \
            _Pragma("unroll")                                                           \
            for (int mt = 0; mt < 4; ++mt)                                              \
                _Pragma("unroll")                                                       \
                for (int nt = 0; nt < 4; ++nt)                                          \
                    acc[mt][nt] = MFMA16(a_[mt], b_[nt], acc[mt][nt]);                  \
            } while (0)

        STG(0, 0);
        STG(1, 32);
        for (int s = 0; s < 15; ++s) {
            int cb = s & 1;
            asm volatile("s_waitcnt vmcnt(4)" ::: "memory");
            __builtin_amdgcn_s_barrier();
            __builtin_amdgcn_sched_barrier(0);
            CMP(cb);
            __builtin_amdgcn_sched_barrier(0);
            __builtin_amdgcn_s_barrier();
            if (s < 14) STG(cb, (s + 2) * 32);
        }
        asm volatile("s_waitcnt vmcnt(0)" ::: "memory");
        __builtin_amdgcn_s_barrier();
        __builtin_amdgcn_sched_barrier(0);
        CMP(1);
        #undef STG
        #undef CMP
        #pragma unroll
        for (int mt = 0; mt < 4; ++mt)
            #pragma unroll
            for (int reg = 0; reg < 4; ++reg) {
                float s = 0.f;
                #pragma unroll
                for (int nt = 0; nt < 4; ++nt) s += acc[mt][nt][reg] * acc[mt][nt][reg];
                s += __shfl_xor(s, 1); s += __shfl_xor(s, 2);
                s += __shfl_xor(s, 4); s += __shfl_xor(s, 8);
                if (cl == 0) red[qr * 64 + mt * 16 + g * 4 + reg][qc] = s;
            }
        __syncthreads();
        if (t < 128) atomicAdd(&x2[(size_t)(b0 + t) * C_N + c], red[t][0] + red[t][1]);
    } else {
        // dots slice: 128 b x 32 q (class c)
        f32x4 acc[2][2];
        #pragma unroll
        for (int mt = 0; mt < 2; ++mt)
            #pragma unroll
            for (int nt = 0; nt < 2; ++nt) acc[mt][nt] = (f32x4){0,0,0,0};
        #pragma unroll
        for (int i = 0; i < 2; ++i) {
            int rb = w * 32 + i * 16;
            int r  = rb + srow;
            int cg = (spos + r) & 3;
            gll16(xb + (size_t)(b0 + r) * D_N + cg * 8, &Xs[0][rb][0]);
        }
        if (w < 2) {
            int rb = w * 16;
            int r  = rb + srow;
            int cg = (spos + r) & 3;
            gll16(ug + ((size_t)c * 32 + r) * D_N + cg * 8, &Os[0][rb][0]);
        }
        __syncthreads();
        for (int s = 0; s < 16; ++s) {
            int cb = s & 1, nb = cb ^ 1;
            if (s < 15) {
                int k1 = (s + 1) * 32;
                #pragma unroll
                for (int i = 0; i < 2; ++i) {
                    int rb = w * 32 + i * 16;
                    int r  = rb + srow;
                    int cg = (spos + r) & 3;
                    gll16(xb + (size_t)(b0 + r) * D_N + k1 + cg * 8, &Xs[nb][rb][0]);
                }
                if (w < 2) {
                    int rb = w * 16;
                    int r  = rb + srow;
                    int cg = (spos + r) & 3;
                    gll16(ug + ((size_t)c * 32 + r) * D_N + k1 + cg * 8, &Os[nb][rb][0]);
                }
            }
            short8 a[2], b[2];
            #pragma unroll
            for (int mt = 0; mt < 2; ++mt) {
                int r = w * 32 + mt * 16 + cl;
                a[mt] = *(const short8*)&Xs[cb][r][((g - r) & 3) * 8];
            }
            #pragma unroll
            for (int nt = 0; nt < 2; ++nt) {
                int r = nt * 16 + cl;
                b[nt] = *(const short8*)&Os[cb][r][((g - r) & 3) * 8];
            }
            #pragma unroll
            for (int mt = 0; mt < 2; ++mt)
                #pragma unroll
                for (int nt = 0; nt < 2; ++nt)
                    acc[mt][nt] = MFMA16(a[mt], b[nt], acc[mt][nt]);
            __syncthreads();
        }
        #pragma unroll
        for (int mt = 0; mt < 2; ++mt)
            #pragma unroll
            for (int reg = 0; reg < 4; ++reg) {
                float v = INFINITY;
                #pragma unroll
                for (int nt = 0; nt < 2; ++nt) {
                    int q = c * 32 + nt * 16 + cl;
                    v = fminf(v, p2g[q] - 2.f * acc[mt][nt][reg]);
                }
                v = fminf(v, __shfl_xor(v, 1)); v = fminf(v, __shfl_xor(v, 2));
                v = fminf(v, __shfl_xor(v, 4)); v = fminf(v, __shfl_xor(v, 8));
                if (cl == 0)
                    minb[(size_t)(b0 + w * 32 + mt * 16 + g * 4 + reg) * C_N + c] = v;
            }
    }

    // ---- common tail: per-tile ticket -> mu -> final ticket -> out ----
    __syncthreads();                          // all lanes' stores/atomics drained (vmcnt 0)
    if (t == 0) {
        __threadfence();                      // release this block's contribution
        unsigned o = atomicAdd(&ttk[z], 1u);
        flg1 = (o == 39u);
        if (flg1) __threadfence();            // acquire: see all 40 contributions
    }
    __syncthreads();
    if (flg1) {
        float s = 0.f;
        if (t < 128) {
            int b = b0 + t, yb = y[b];
            float pos = 0.f, neg = INFINITY;
            #pragma unroll
            for (int cc = 0; cc < 8; ++cc) {
                float dd = x2[(size_t)b * C_N + cc] + minb[(size_t)b * C_N + cc];
                if (cc == yb) pos = dd; else neg = fminf(neg, dd);
            }
            float mu = (pos - neg) / (pos + neg);
            s = 1.f / (1.f + expf(-mu));
        }
        #pragma unroll
        for (int off = 32; off > 0; off >>= 1) s += __shfl_down(s, off);
        if ((t & 63) == 0) rr[t >> 6] = s;
        __syncthreads();
        if (t == 0) {
            musum[z] = rr[0] + rr[1] + rr[2] + rr[3];
            __threadfence();
            unsigned o2 = atomicAdd(ftk, 1u);
            flg2 = (o2 == 31u);
            if (flg2) __threadfence();
        }
        __syncthreads();
        if (flg2) {
            float a1 = (t < 32) ? musum[t] : 0.f;
            float a2 = ossp[2 * t] + ossp[2 * t + 1];
            #pragma unroll
            for (int off = 32; off > 0; off >>= 1) {
                a1 += __shfl_down(a1, off);
                a2 += __shfl_down(a2, off);
            }
            if ((t & 63) == 0) { rr[t >> 6] = a1; rr2[t >> 6] = a2; }
            __syncthreads();
            if (t == 0) {
                float ls  = rr[0] + rr[1] + rr[2] + rr[3];
                float oss = rr2[0] + rr2[1] + rr2[2] + rr2[3];
                out[0] = ls * (1.f / (float)B_N) + 0.01f * sqrtf(oss);
            }
        }
    }
}

extern "C" void kernel_launch(void* const* d_in, const int* in_sizes, int n_in,
                              void* d_out, int out_size, void* d_ws, size_t ws_size,
                              hipStream_t stream) {
    (void)in_sizes; (void)n_in; (void)out_size; (void)ws_size;
    const float* x     = (const float*)d_in[0];
    const int*   y     = (const int*)d_in[1];
    const float* prot  = (const float*)d_in[2];
    const float* omega = (const float*)d_in[3];

    char* ws = (char*)d_ws;
    unsigned* tk    = (unsigned*)(ws + TK_OFF);
    unsigned* ttk   = (unsigned*)(ws + TTK_OFF);
    unsigned* ftk   = (unsigned*)(ws + FTK_OFF);
    float*    p2g   = (float*)(ws + P2G_OFF);
    float*    x2    = (float*)(ws + X2_OFF);
    float*    ossp  = (float*)(ws + OSSP_OFF);
    float*    musum = (float*)(ws + MUSUM_OFF);
    ushort_t* xb    = (ushort_t*)(ws + XB_OFF);
    ushort_t* omb   = (ushort_t*)(ws + OMB_OFF);
    ushort_t* tpg   = (ushort_t*)(ws + TPG_OFF);
    ushort_t* ug    = (ushort_t*)(ws + UG_OFF);
    ushort_t* ombT  = (ushort_t*)(ws + OMBT_OFF);
    float*    minb  = (float*)(ws + MINB_OFF);  // aliases ombT — safe: stream-ordered after k_tpu

    k_cast <<<1544, 256, 0, stream>>>(x, omega, xb, omb, ombT, ossp, ws);
    k_tpu  <<<128, 256, 0, stream>>>(prot, omb, ombT, tpg, ug, p2g, tk);
    k_x2dm <<<dim3(5, C_N, B_N / 128), 256, 0, stream>>>(xb, omb, ug, p2g, x2, minb,
                                                         y, ossp, musum, ttk, ftk,
                                                         (float*)d_out);
}

// Round 8
// 124.307 us; speedup vs baseline: 1.2269x; 1.2269x over previous
//
#include <hip/hip_runtime.h>
#include <math.h>

typedef unsigned short ushort_t;
typedef __attribute__((ext_vector_type(8))) short short8;
typedef __attribute__((ext_vector_type(4))) float f32x4;

#define B_N 4096
#define D_N 512
#define P_N 256
#define C_N 8

// workspace byte offsets
// zeroed region [0, 132352) — written only by k_cast zero-blocks, consumed by later kernels
#define ACC_OFF   0                          // [0]=loss_sum, [2]=mu ticket (zeroed)
#define P2G_OFF   256                        // p2 grouped [256] f32 (zeroed)
#define X2_OFF    1280                       // x2 [B][C] f32 (zeroed, atomic-accumulated), ends 132352
#define ZERO_BYTES 132352
// non-zeroed (overwritten before read)
#define OSSP_OFF  132352                     // omega-sumsq partials [512] f32 (slot stores)
#define XB_OFF    135168                     // x bf16 [B][D]
#define OMB_OFF   (XB_OFF + B_N*D_N*2)       // omega bf16 [C][D][D]
#define TPG_OFF   (OMB_OFF + C_N*D_N*D_N*2)  // tp grouped bf16 [C][32][D]
#define UG_OFF    (TPG_OFF + P_N*D_N*2)      // u grouped bf16 [C][32][D]
#define OMBT_OFF  (UG_OFF + P_N*D_N*2)       // omega^T bf16 [C][D][D]
#define MINB_OFF  OMBT_OFF                   // minb [B][C] f32 — aliases ombT (dead after k_u)

#define MFMA16(a, b, c) __builtin_amdgcn_mfma_f32_16x16x32_bf16(a, b, c, 0, 0, 0)

__device__ inline ushort_t f2bf(float f) {
    union { float f; unsigned u; } v; v.f = f;
    unsigned r = v.u + 0x7FFFu + ((v.u >> 16) & 1u);
    return (ushort_t)(r >> 16);
}

// async global->LDS, 16 B per lane. LDS dst must be wave-uniform; HW writes base + lane*16.
__device__ __forceinline__ void gll16(const ushort_t* g, ushort_t* l) {
    __builtin_amdgcn_global_load_lds((const __attribute__((address_space(1))) void*)g,
                                     (__attribute__((address_space(3))) void*)l, 16, 0, 0);
}

// ---------- fused casts + workspace zeroing (R7-verified clean) ----------
// blocks [0,1024): cast x; [1024,1536): cast omega (+ossp slot); [1536,1544): zero accs/p2g/x2
__global__ void k_cast(const float* __restrict__ x, const float* __restrict__ omega,
                       ushort_t* __restrict__ xb, ushort_t* __restrict__ omb,
                       ushort_t* __restrict__ ombT, float* __restrict__ ossp,
                       char* __restrict__ zbase) {
    __shared__ ushort_t T[64][72];
    __shared__ float red[4];
    int t = threadIdx.x;
    if (blockIdx.x >= 1536) {
        int zb = blockIdx.x - 1536;
        uint4 z4 = {0, 0, 0, 0};
        for (size_t off = ((size_t)zb * 256 + t) * 16; off < (size_t)ZERO_BYTES; off += 8u * 256u * 16u)
            *(uint4*)(zbase + off) = z4;
        return;
    }
    if (blockIdx.x < 1024) {
        int idx = blockIdx.x * 256 + t;
        const float4* x4 = (const float4*)x;
        float4 a = x4[idx * 2], b = x4[idx * 2 + 1];
        union { ushort_t s[8]; uint4 v; } o;
        o.s[0] = f2bf(a.x); o.s[1] = f2bf(a.y); o.s[2] = f2bf(a.z); o.s[3] = f2bf(a.w);
        o.s[4] = f2bf(b.x); o.s[5] = f2bf(b.y); o.s[6] = f2bf(b.z); o.s[7] = f2bf(b.w);
        ((uint4*)xb)[idx] = o.v;
        return;
    }
    int bid = blockIdx.x - 1024;
    int c = bid >> 6, by = (bid >> 3) & 7, bx = bid & 7;
    int r0 = by * 64, c0 = bx * 64;
    int r = t >> 2, seg = t & 3;
    const float* src = omega + ((size_t)c * D_N + r0 + r) * D_N + c0 + seg * 16;
    float4 v0 = ((const float4*)src)[0], v1 = ((const float4*)src)[1];
    float4 v2 = ((const float4*)src)[2], v3 = ((const float4*)src)[3];
    float s = v0.x*v0.x + v0.y*v0.y + v0.z*v0.z + v0.w*v0.w
            + v1.x*v1.x + v1.y*v1.y + v1.z*v1.z + v1.w*v1.w
            + v2.x*v2.x + v2.y*v2.y + v2.z*v2.z + v2.w*v2.w
            + v3.x*v3.x + v3.y*v3.y + v3.z*v3.z + v3.w*v3.w;
    union { ushort_t s[16]; uint4 v[2]; } o;
    float vv[16] = {v0.x,v0.y,v0.z,v0.w, v1.x,v1.y,v1.z,v1.w,
                    v2.x,v2.y,v2.z,v2.w, v3.x,v3.y,v3.z,v3.w};
    #pragma unroll
    for (int j = 0; j < 16; ++j) o.s[j] = f2bf(vv[j]);
    uint4* dst = (uint4*)(omb + ((size_t)c * D_N + r0 + r) * D_N + c0 + seg * 16);
    dst[0] = o.v[0]; dst[1] = o.v[1];
    #pragma unroll
    for (int j = 0; j < 16; ++j) T[seg * 16 + j][r] = o.s[j];
    __syncthreads();
    int jr = t >> 2, sg2 = t & 3;
    uint4 w0 = *(uint4*)&T[jr][sg2 * 16];
    uint4 w1 = *(uint4*)&T[jr][sg2 * 16 + 8];
    uint4* dstT = (uint4*)(ombT + ((size_t)c * D_N + c0 + jr) * D_N + r0 + sg2 * 16);
    dstT[0] = w0; dstT[1] = w1;
    #pragma unroll
    for (int off = 32; off > 0; off >>= 1) s += __shfl_down(s, off);
    if ((t & 63) == 0) red[t >> 6] = s;
    __syncthreads();
    if (t == 0) ossp[bid] = red[0] + red[1] + red[2] + red[3];   // slot store — no atomic, no zeroing
}

// ---------- tp[c*32+m][i] = sum_k prot[c+8m][k] * om_c[i][k]; p2 fused (R6 verbatim) ----------
__global__ __launch_bounds__(256) void k_tp(const float* __restrict__ prot,
                                            const ushort_t* __restrict__ omb,
                                            ushort_t* __restrict__ tpg,
                                            float* __restrict__ p2g) {
    int i0 = blockIdx.x * 64, c = blockIdx.y;
    __shared__ ushort_t As[32][72];
    __shared__ ushort_t Bs[64][72];
    int t = threadIdx.x, w = t >> 6, lane = t & 63;
    int g = lane >> 4, cl = lane & 15;
    f32x4 acc[2] = {{0,0,0,0},{0,0,0,0}};
    for (int k0 = 0; k0 < D_N; k0 += 64) {
        __syncthreads();
        {
            int m = t >> 3, seg = t & 7;
            const float* ap = prot + ((size_t)(c + 8 * m)) * D_N + k0 + seg * 8;
            float4 u0 = ((const float4*)ap)[0], u1 = ((const float4*)ap)[1];
            union { ushort_t s[8]; uint4 v; } o;
            o.s[0]=f2bf(u0.x); o.s[1]=f2bf(u0.y); o.s[2]=f2bf(u0.z); o.s[3]=f2bf(u0.w);
            o.s[4]=f2bf(u1.x); o.s[5]=f2bf(u1.y); o.s[6]=f2bf(u1.z); o.s[7]=f2bf(u1.w);
            *(uint4*)&As[m][seg * 8] = o.v;
        }
        {
            int r = t >> 2, sg = t & 3;
            const uint4* bp = (const uint4*)(omb + ((size_t)c * D_N + i0 + r) * D_N + k0 + sg * 16);
            *(uint4*)&Bs[r][sg * 16] = bp[0];
            *(uint4*)&Bs[r][sg * 16 + 8] = bp[1];
        }
        __syncthreads();
        #pragma unroll
        for (int kk = 0; kk < 2; ++kk) {
            int koff = kk * 32 + g * 8;
            short8 bfr = *(const short8*)&Bs[w * 16 + cl][koff];
            #pragma unroll
            for (int mt = 0; mt < 2; ++mt) {
                short8 afr = *(const short8*)&As[mt * 16 + cl][koff];
                acc[mt] = MFMA16(afr, bfr, acc[mt]);
            }
        }
    }
    #pragma unroll
    for (int mt = 0; mt < 2; ++mt)
        #pragma unroll
        for (int reg = 0; reg < 4; ++reg) {
            float v = acc[mt][reg];
            int m = mt * 16 + g * 4 + reg;
            int i = i0 + w * 16 + cl;
            tpg[((size_t)c * 32 + m) * D_N + i] = f2bf(v);
            float s = v * v;
            s += __shfl_xor(s, 1); s += __shfl_xor(s, 2);
            s += __shfl_xor(s, 4); s += __shfl_xor(s, 8);
            if (cl == 0) atomicAdd(&p2g[c * 32 + m], s);
        }
}

// ---------- u[c*32+m][j] = sum_i tp[c*32+m][i] * om_c[i][j] (R6 verbatim) ----------
__global__ __launch_bounds__(256) void k_u(const ushort_t* __restrict__ tpg,
                                           const ushort_t* __restrict__ ombT,
                                           ushort_t* __restrict__ ug) {
    int j0 = blockIdx.x * 64, c = blockIdx.y;
    __shared__ ushort_t As[32][72];
    __shared__ ushort_t Bs[64][72];
    int t = threadIdx.x, w = t >> 6, lane = t & 63;
    int g = lane >> 4, cl = lane & 15;
    f32x4 acc[2] = {{0,0,0,0},{0,0,0,0}};
    for (int k0 = 0; k0 < D_N; k0 += 64) {
        __syncthreads();
        {
            int m = t >> 3, seg = t & 7;
            *(uint4*)&As[m][seg * 8] =
                *(const uint4*)(tpg + ((size_t)c * 32 + m) * D_N + k0 + seg * 8);
        }
        {
            int r = t >> 2, sg = t & 3;
            const uint4* bp = (const uint4*)(ombT + ((size_t)c * D_N + j0 + r) * D_N + k0 + sg * 16);
            *(uint4*)&Bs[r][sg * 16] = bp[0];
            *(uint4*)&Bs[r][sg * 16 + 8] = bp[1];
        }
        __syncthreads();
        #pragma unroll
        for (int kk = 0; kk < 2; ++kk) {
            int koff = kk * 32 + g * 8;
            short8 bfr = *(const short8*)&Bs[w * 16 + cl][koff];
            #pragma unroll
            for (int mt = 0; mt < 2; ++mt) {
                short8 afr = *(const short8*)&As[mt * 16 + cl][koff];
                acc[mt] = MFMA16(afr, bfr, acc[mt]);
            }
        }
    }
    #pragma unroll
    for (int mt = 0; mt < 2; ++mt)
        #pragma unroll
        for (int reg = 0; reg < 4; ++reg) {
            int m = mt * 16 + g * 4 + reg;
            int j = j0 + w * 16 + cl;
            ug[((size_t)c * 32 + m) * D_N + j] = f2bf(acc[mt][reg]);
        }
}

// ---------- fused x2 + dots-min: grid (5, 8, 32) (R6 verbatim — do not perturb codegen) ----------
// blockIdx.x 0..3: x2 tile (128b x 128i), counted-vmcnt pipeline (T4).
// blockIdx.x == 4: dots slice.
// waves_per_eu(3,3): 170-reg budget, VGPR 112, no spill, 3 blocks/CU.
__global__ __attribute__((amdgpu_flat_work_group_size(256, 256), amdgpu_waves_per_eu(3, 3)))
void k_x2d(const ushort_t* __restrict__ xb,
           const ushort_t* __restrict__ omb,
           const ushort_t* __restrict__ ug,
           const float* __restrict__ p2g,
           float* __restrict__ x2,
           float* __restrict__ minb) {
    int c  = blockIdx.y;
    int b0 = blockIdx.z * 128;
    int t = threadIdx.x, w = t >> 6, lane = t & 63;
    int g = lane >> 4, cl = lane & 15;
    int srow = lane >> 2, spos = lane & 3;   // staging: 16 rows x 4 chunk-positions per gll

    __shared__ ushort_t Xs[2][128][32];
    __shared__ ushort_t Os[2][128][32];      // dots path uses rows 0..31 as Us
    __shared__ float red[128][2];

    if (blockIdx.x < 4) {
        int i0 = blockIdx.x * 128;
        int qr = w >> 1, qc = w & 1;
        f32x4 acc[4][4];
        #pragma unroll
        for (int mt = 0; mt < 4; ++mt)
            #pragma unroll
            for (int nt = 0; nt < 4; ++nt) acc[mt][nt] = (f32x4){0,0,0,0};

        // stage slab k1 into buffer bf: 4 gll16 per wave (X,O,X,O)
        #define STG(bf, k1) do {                                                        \
            _Pragma("unroll")                                                           \
            for (int i = 0; i < 2; ++i) {                                               \
                int rb = w * 32 + i * 16;                                               \
                int r  = rb + srow;                                                     \
                int cg = (spos + r) & 3;                                                \
                gll16(xb + (size_t)(b0 + r) * D_N + (k1) + cg * 8, &Xs[bf][rb][0]);     \
                gll16(omb + ((size_t)c * D_N + i0 + r) * D_N + (k1) + cg * 8,           \
                      &Os[bf][rb][0]);                                                  \
            } } while (0)

        #define CMP(cb) do {                                                            \
            short8 a_[4], b_[4];                                                        \
            _Pragma("unroll")                                                           \
            for (int mt = 0; mt < 4; ++mt) {                                            \
                int r = qr * 64 + mt * 16 + cl;                                         \
                a_[mt] = *(const short8*)&Xs[cb][r][((g - r) & 3) * 8];                 \
            }                                                                           \
            _Pragma("unroll")                                                           \
            for (int nt = 0; nt < 4; ++nt) {                                            \
                int r = qc * 64 + nt * 16 + cl;                                         \
                b_[nt] = *(const short8*)&Os[cb][r][((g - r) & 3) * 8];                 \
            }                                                                           \
            _Pragma("unroll")                                                           \
            for (int mt = 0; mt < 4; ++mt)                                              \
                _Pragma("unroll")                                                       \
                for (int nt = 0; nt < 4; ++nt)                                          \
                    acc[mt][nt] = MFMA16(a_[mt], b_[nt], acc[mt][nt]);                  \
            } while (0)

        STG(0, 0);
        STG(1, 32);
        for (int s = 0; s < 15; ++s) {
            int cb = s & 1;
            // wait own slab-s loads (4 of slab s+1 stay in flight), then block-sync
            asm volatile("s_waitcnt vmcnt(4)" ::: "memory");
            __builtin_amdgcn_s_barrier();
            __builtin_amdgcn_sched_barrier(0);
            CMP(cb);
            __builtin_amdgcn_sched_barrier(0);
            __builtin_amdgcn_s_barrier();     // all reads of buf cb done -> safe to refill
            if (s < 14) STG(cb, (s + 2) * 32);
        }
        asm volatile("s_waitcnt vmcnt(0)" ::: "memory");
        __builtin_amdgcn_s_barrier();
        __builtin_amdgcn_sched_barrier(0);
        CMP(1);
        #undef STG
        #undef CMP
        // epilogue: row sum-of-squares -> red -> atomic
        #pragma unroll
        for (int mt = 0; mt < 4; ++mt)
            #pragma unroll
            for (int reg = 0; reg < 4; ++reg) {
                float s = 0.f;
                #pragma unroll
                for (int nt = 0; nt < 4; ++nt) s += acc[mt][nt][reg] * acc[mt][nt][reg];
                s += __shfl_xor(s, 1); s += __shfl_xor(s, 2);
                s += __shfl_xor(s, 4); s += __shfl_xor(s, 8);
                if (cl == 0) red[qr * 64 + mt * 16 + g * 4 + reg][qc] = s;
            }
        __syncthreads();
        if (t < 128) atomicAdd(&x2[(size_t)(b0 + t) * C_N + c], red[t][0] + red[t][1]);
    } else {
        // dots slice: 128 b x 32 q (class c)
        f32x4 acc[2][2];
        #pragma unroll
        for (int mt = 0; mt < 2; ++mt)
            #pragma unroll
            for (int nt = 0; nt < 2; ++nt) acc[mt][nt] = (f32x4){0,0,0,0};
        #pragma unroll
        for (int i = 0; i < 2; ++i) {
            int rb = w * 32 + i * 16;
            int r  = rb + srow;
            int cg = (spos + r) & 3;
            gll16(xb + (size_t)(b0 + r) * D_N + cg * 8, &Xs[0][rb][0]);
        }
        if (w < 2) {
            int rb = w * 16;
            int r  = rb + srow;
            int cg = (spos + r) & 3;
            gll16(ug + ((size_t)c * 32 + r) * D_N + cg * 8, &Os[0][rb][0]);
        }
        __syncthreads();
        for (int s = 0; s < 16; ++s) {
            int cb = s & 1, nb = cb ^ 1;
            if (s < 15) {
                int k1 = (s + 1) * 32;
                #pragma unroll
                for (int i = 0; i < 2; ++i) {
                    int rb = w * 32 + i * 16;
                    int r  = rb + srow;
                    int cg = (spos + r) & 3;
                    gll16(xb + (size_t)(b0 + r) * D_N + k1 + cg * 8, &Xs[nb][rb][0]);
                }
                if (w < 2) {
                    int rb = w * 16;
                    int r  = rb + srow;
                    int cg = (spos + r) & 3;
                    gll16(ug + ((size_t)c * 32 + r) * D_N + k1 + cg * 8, &Os[nb][rb][0]);
                }
            }
            short8 a[2], b[2];
            #pragma unroll
            for (int mt = 0; mt < 2; ++mt) {
                int r = w * 32 + mt * 16 + cl;
                a[mt] = *(const short8*)&Xs[cb][r][((g - r) & 3) * 8];
            }
            #pragma unroll
            for (int nt = 0; nt < 2; ++nt) {
                int r = nt * 16 + cl;
                b[nt] = *(const short8*)&Os[cb][r][((g - r) & 3) * 8];
            }
            #pragma unroll
            for (int mt = 0; mt < 2; ++mt)
                #pragma unroll
                for (int nt = 0; nt < 2; ++nt)
                    acc[mt][nt] = MFMA16(a[mt], b[nt], acc[mt][nt]);
            __syncthreads();
        }
        #pragma unroll
        for (int mt = 0; mt < 2; ++mt)
            #pragma unroll
            for (int reg = 0; reg < 4; ++reg) {
                float v = INFINITY;
                #pragma unroll
                for (int nt = 0; nt < 2; ++nt) {
                    int q = c * 32 + nt * 16 + cl;
                    v = fminf(v, p2g[q] - 2.f * acc[mt][nt][reg]);
                }
                v = fminf(v, __shfl_xor(v, 1)); v = fminf(v, __shfl_xor(v, 2));
                v = fminf(v, __shfl_xor(v, 4)); v = fminf(v, __shfl_xor(v, 8));
                if (cl == 0)
                    minb[(size_t)(b0 + w * 32 + mt * 16 + g * 4 + reg) * C_N + c] = v;
            }
    }
}

// ---------- per-row mu -> sigmoid -> sum; last block sums ossp + writes final loss ----------
__global__ void k_mu(const float* __restrict__ x2, const float* __restrict__ minb,
                     const int* __restrict__ y, const float* __restrict__ ossp,
                     float* __restrict__ accs, float* __restrict__ out) {
    int t = threadIdx.x;
    int b = blockIdx.x * 256 + t;
    int yb = y[b];
    float d[8];
    #pragma unroll
    for (int cc = 0; cc < 8; ++cc)
        d[cc] = x2[(size_t)b * C_N + cc] + minb[(size_t)b * C_N + cc];
    float pos = d[yb];
    float neg = INFINITY;
    #pragma unroll
    for (int cc = 0; cc < 8; ++cc)
        if (cc != yb) neg = fminf(neg, d[cc]);
    float mu = (pos - neg) / (pos + neg);
    float s = 1.f / (1.f + expf(-mu));
    #pragma unroll
    for (int off = 32; off > 0; off >>= 1) s += __shfl_down(s, off);
    __shared__ float red[4];
    __shared__ bool last;
    if ((t & 63) == 0) red[t >> 6] = s;
    __syncthreads();
    if (t == 0) {
        atomicAdd(accs, red[0] + red[1] + red[2] + red[3]);
        __threadfence();
        unsigned n = atomicAdd((unsigned*)(accs + 2), 1u);
        last = (n == (unsigned)(B_N / 256 - 1));
        if (last) __threadfence();
    }
    __syncthreads();
    if (last) {
        float a2 = ossp[t] + ossp[t + 256];
        #pragma unroll
        for (int off = 32; off > 0; off >>= 1) a2 += __shfl_down(a2, off);
        if ((t & 63) == 0) red[t >> 6] = a2;
        __syncthreads();
        if (t == 0) {
            float ls  = atomicAdd(accs, 0.f);        // full sum (all tickets in)
            float oss = red[0] + red[1] + red[2] + red[3];
            out[0] = ls * (1.f / (float)B_N) + 0.01f * sqrtf(oss);
        }
    }
}

extern "C" void kernel_launch(void* const* d_in, const int* in_sizes, int n_in,
                              void* d_out, int out_size, void* d_ws, size_t ws_size,
                              hipStream_t stream) {
    (void)in_sizes; (void)n_in; (void)out_size; (void)ws_size;
    const float* x     = (const float*)d_in[0];
    const int*   y     = (const int*)d_in[1];
    const float* prot  = (const float*)d_in[2];
    const float* omega = (const float*)d_in[3];

    char* ws = (char*)d_ws;
    float*    accs = (float*)(ws + ACC_OFF);
    float*    p2g  = (float*)(ws + P2G_OFF);
    float*    x2   = (float*)(ws + X2_OFF);
    float*    ossp = (float*)(ws + OSSP_OFF);
    ushort_t* xb   = (ushort_t*)(ws + XB_OFF);
    ushort_t* omb  = (ushort_t*)(ws + OMB_OFF);
    ushort_t* tpg  = (ushort_t*)(ws + TPG_OFF);
    ushort_t* ug   = (ushort_t*)(ws + UG_OFF);
    ushort_t* ombT = (ushort_t*)(ws + OMBT_OFF);
    float*    minb = (float*)(ws + MINB_OFF);  // aliases ombT — safe: stream-ordered after k_u

    k_cast <<<1544, 256, 0, stream>>>(x, omega, xb, omb, ombT, ossp, ws);
    k_tp   <<<dim3(8, C_N), 256, 0, stream>>>(prot, omb, tpg, p2g);
    k_u    <<<dim3(8, C_N), 256, 0, stream>>>(tpg, ombT, ug);
    k_x2d  <<<dim3(5, C_N, B_N / 128), 256, 0, stream>>>(xb, omb, ug, p2g, x2, minb);
    k_mu   <<<B_N / 256, 256, 0, stream>>>(x2, minb, y, ossp, accs, (float*)d_out);
}